// Round 2
// 495.717 us; speedup vs baseline: 1.3419x; 1.3419x over previous
//
#include <hip/hip_runtime.h>
#include <hip/hip_bf16.h>
#include <math.h>

// HNNLayer fused kernel for MI355X (gfx950).
// Per row (C=1): t = acosh(h0)*y/||y||; tn = layernorm(t)*gamma+beta;
// v = tn @ W[1:,1:]^T (bf16 MFMA); hyperbolic bias-transport epilogue.
// expmap0/logmap0 round trips are exact identities and are elided.
//
// V2 (jt-split): each wave owns ALL 64 rows x 64 cols (cols [64w,64w+64)).
//  - global Wb loads per wave: 128 -> 32 (4x less L1/L2 traffic, footprint
//    16KiB/kk is L1-resident)
//  - gamma/beta LDS reads hoisted out of the it-loop (8-way-conflict reads 4x fewer)
//  - all 16 h float4 loads issued up front (HBM latency overlapped)
//  - row reductions cross waves via LDS partials + two 64-thread scalar passes

#define MINV 1e-15f

typedef __bf16 bf16x8 __attribute__((ext_vector_type(8)));
typedef __bf16 bf16x4 __attribute__((ext_vector_type(4)));
typedef float floatx4 __attribute__((ext_vector_type(4)));

// ---- prep: W[1:,1:] -> bf16 [256x256] (row j = out col), bias scalars ----
__global__ __launch_bounds__(256) void prep_kernel(const float* __restrict__ W,
                                                   const float* __restrict__ bias,
                                                   __bf16* __restrict__ Wb,
                                                   float* __restrict__ scal) {
  int b = blockIdx.x;
  if (b < 64) {
    int idx = b * 1024 + threadIdx.x * 4;
    int j = idx >> 8;
    float4 w;
    if (j < 255) w = *(const float4*)(W + idx + 256);
    else w = make_float4(0.f, 0.f, 0.f, 0.f);
    bf16x4 o;
    o[0] = (__bf16)w.x; o[1] = (__bf16)w.y; o[2] = (__bf16)w.z; o[3] = (__bf16)w.w;
    *(bf16x4*)(Wb + idx) = o;
  } else if (threadIdx.x < 64) {
    int l = threadIdx.x;
    float4 bv = *(const float4*)(bias + l * 4);
    float s = bv.x * bv.x + bv.y * bv.y + bv.z * bv.z + bv.w * bv.w;
    if (l == 0) s -= bv.x * bv.x;
    for (int m = 1; m < 64; m <<= 1) s += __shfl_xor(s, m);
    if (l == 0) {
      float nb = sqrtf(s);
      float normu = fminf(nb, 1000.0f);
      float th = fmaxf(normu, MINV);
      scal[0] = coshf(th);          // c1
      scal[1] = sinhf(th) / th;     // s1
      scal[2] = s;                  // ||b1||^2
    }
  }
}

// ---- main fused kernel: 64 rows/block, wave w owns cols [64w, 64w+64) ----
__global__ __launch_bounds__(256, 4) void hnn_kernel(const float* __restrict__ h,
                                                     const __bf16* __restrict__ Wb,
                                                     const float* __restrict__ bias,
                                                     const float* __restrict__ gamma,
                                                     const float* __restrict__ beta,
                                                     const float* __restrict__ scal,
                                                     float* __restrict__ out) {
  __shared__ __bf16 Xs[64][264];            // +8 pad -> 528B row stride (2-way reads)
  __shared__ __align__(16) float gs[256];   // gs[0]=0, gs[c]=gamma[c-1]
  __shared__ __align__(16) float bs[256];
  __shared__ float partA[64][4];            // sum v^2      [row][wave]
  __shared__ float partB[64][4];            // sum v*b1     [row][wave]
  __shared__ float rowAB[64][2];            // per-row {A_r, B_r}
  __shared__ float partX[64][4];            // sum x^2      [row][wave]
  __shared__ float rowS[64];                // per-row sinh(n2)/n2

  const int tid = threadIdx.x;
  const int wave = tid >> 6;
  const int lane = tid & 63;
  const int lane16 = lane & 15;
  const int quad = lane >> 4;
  const int rowBlock = blockIdx.x * 64;

  // ---------- issue all h loads up front (16 float4 / lane) ----------
  float4 hv[4][4];
#pragma unroll
  for (int it = 0; it < 4; ++it) {
    const int row = rowBlock + wave * 16 + it * 4 + quad;
    const float4* hp = (const float4*)(h + row * 256 + lane16 * 16);
    hv[it][0] = hp[0]; hv[it][1] = hp[1]; hv[it][2] = hp[2]; hv[it][3] = hp[3];
  }

  if (tid < 255) { gs[tid + 1] = gamma[tid]; bs[tid + 1] = beta[tid]; }
  else { gs[0] = 0.f; bs[0] = 0.f; }
  __syncthreads();

  // gamma/beta hoisted into registers (loop-invariant across its)
  float4 gv[4], bv[4];
#pragma unroll
  for (int q = 0; q < 4; ++q) {
    gv[q] = *(const float4*)(gs + lane16 * 16 + q * 4);
    bv[q] = *(const float4*)(bs + lane16 * 16 + q * 4);
  }

  // ---------- Phase A: logmap0 + layernorm -> Xs (bf16) ----------
#pragma unroll
  for (int it = 0; it < 4; ++it) {
    const int lrow = wave * 16 + it * 4 + quad;
    float vals[16] = {hv[it][0].x, hv[it][0].y, hv[it][0].z, hv[it][0].w,
                      hv[it][1].x, hv[it][1].y, hv[it][1].z, hv[it][1].w,
                      hv[it][2].x, hv[it][2].y, hv[it][2].z, hv[it][2].w,
                      hv[it][3].x, hv[it][3].y, hv[it][3].z, hv[it][3].w};
    float s1l = 0.f, s2l = 0.f;
#pragma unroll
    for (int i = 0; i < 16; ++i) { s1l += vals[i]; s2l += vals[i] * vals[i]; }
    if (lane16 == 0) { s1l -= vals[0]; s2l -= vals[0] * vals[0]; }
#pragma unroll
    for (int m = 1; m < 16; m <<= 1) {
      s1l += __shfl_xor(s1l, m);
      s2l += __shfl_xor(s2l, m);
    }
    float h0 = __shfl(vals[0], lane & 48);   // group base lane holds h[row][0]
    float yn = fmaxf(sqrtf(s2l), MINV);
    float xc = fmaxf(h0, 1.0f + 1e-7f);
    float theta = __logf(xc + sqrtf(xc * xc - 1.0f));   // acosh, x >= ~2.6 here
    float s = theta / yn;                    // t[k] = s*y[k]
    float mu = s * s1l * (1.0f / 255.0f);
    float var = s * s * (s2l * (1.0f / 255.0f)) - mu * mu;
    float rstd = rsqrtf(var + 1e-5f);
    float a = s * rstd;
    float bshift = -mu * rstd;
    bf16x8 o0, o1;
#pragma unroll
    for (int q = 0; q < 4; ++q) {
      float4 g4 = gv[q];
      float4 b4 = bv[q];
      float t0 = (a * vals[q * 4 + 0] + bshift) * g4.x + b4.x;
      float t1 = (a * vals[q * 4 + 1] + bshift) * g4.y + b4.y;
      float t2 = (a * vals[q * 4 + 2] + bshift) * g4.z + b4.z;
      float t3 = (a * vals[q * 4 + 3] + bshift) * g4.w + b4.w;
      if (q < 2) {
        o0[q * 4 + 0] = (__bf16)t0; o0[q * 4 + 1] = (__bf16)t1;
        o0[q * 4 + 2] = (__bf16)t2; o0[q * 4 + 3] = (__bf16)t3;
      } else {
        o1[(q - 2) * 4 + 0] = (__bf16)t0; o1[(q - 2) * 4 + 1] = (__bf16)t1;
        o1[(q - 2) * 4 + 2] = (__bf16)t2; o1[(q - 2) * 4 + 3] = (__bf16)t3;
      }
    }
    *(bf16x8*)(&Xs[lrow][lane16 * 16]) = o0;
    *(bf16x8*)(&Xs[lrow][lane16 * 16 + 8]) = o1;
  }
  __syncthreads();

  // ---------- Phase B: v = tn @ Wb^T ; wave w: 64 rows x cols [64w,64w+64) ----------
  floatx4 acc[4][4];                        // [rt][jt]
#pragma unroll
  for (int rt = 0; rt < 4; ++rt)
#pragma unroll
    for (int jt = 0; jt < 4; ++jt) acc[rt][jt] = (floatx4){0.f, 0.f, 0.f, 0.f};

  const int colBase = wave * 64;
  const __bf16* wbase = Wb + (colBase + lane16) * 256 + quad * 8;
  const __bf16* xbase = &Xs[lane16][quad * 8];

#pragma unroll
  for (int kk = 0; kk < 8; ++kk) {
    bf16x8 bfr[4], afr[4];
#pragma unroll
    for (int jt = 0; jt < 4; ++jt)
      bfr[jt] = *(const bf16x8*)(wbase + jt * 4096 + kk * 32);
#pragma unroll
    for (int rt = 0; rt < 4; ++rt)
      afr[rt] = *(const bf16x8*)(xbase + rt * 4224 + kk * 32);   // rt*16 rows * 264
#pragma unroll
    for (int rt = 0; rt < 4; ++rt)
#pragma unroll
      for (int jt = 0; jt < 4; ++jt)
        acc[rt][jt] = __builtin_amdgcn_mfma_f32_16x16x32_bf16(afr[rt], bfr[jt],
                                                              acc[rt][jt], 0, 0, 0);
  }

  // ---------- Phase C: hyperbolic epilogue (cross-wave row reductions) ----------
  float bb1[4];
#pragma unroll
  for (int jt = 0; jt < 4; ++jt) {
    int c = colBase + jt * 16 + lane16;
    bb1[jt] = (c < 255) ? bias[c + 1] : 0.f;
  }

  // pass 1: per-row partials of sum(v^2), sum(v*b1) over this wave's 64 cols
#pragma unroll
  for (int rt = 0; rt < 4; ++rt) {
#pragma unroll
    for (int e = 0; e < 4; ++e) {
      float sv2 = 0.f, svb = 0.f;
#pragma unroll
      for (int jt = 0; jt < 4; ++jt) {
        float v = acc[rt][jt][e];
        sv2 += v * v;
        svb += v * bb1[jt];
      }
#pragma unroll
      for (int m = 1; m < 16; m <<= 1) {
        sv2 += __shfl_xor(sv2, m);
        svb += __shfl_xor(svb, m);
      }
      if (lane16 == 0) {
        int r = rt * 16 + quad * 4 + e;
        partA[r][wave] = sv2;
        partB[r][wave] = svb;
      }
    }
  }
  __syncthreads();

  // pass 2: one thread per row computes the transport/expmap scalars
  if (tid < 64) {
    float sv2 = partA[tid][0] + partA[tid][1] + partA[tid][2] + partA[tid][3];
    float svb = partB[tid][0] + partB[tid][1] + partB[tid][2] + partB[tid][3];
    const float c1 = scal[0];
    const float s1s = scal[1];
    const float tb2 = scal[2];
    float n = fmaxf(sqrtf(sv2), MINV);
    float inv_n = 1.0f / n;
    float alpha = svb * inv_n;
    float ex = __expf(n);
    float iex = 1.0f / ex;
    float ch = 0.5f * (ex + iex), sh = 0.5f * (ex - iex);
    float beta_ = c1 * sh + s1s * alpha * (ch - 1.0f);
    float rn2 = beta_ * beta_ + 2.0f * beta_ * s1s * alpha + s1s * s1s * tb2;
    float rn = sqrtf(fmaxf(rn2, 0.f));
    float res0 = sqrtf(1.0f + rn2);
    float th3 = __logf(res0 + rn);           // acosh(sqrt(1+rn2))
    float sc3 = th3 / fmaxf(rn, MINV);
    rowAB[tid][0] = sc3 * beta_ * inv_n;     // A_r (scales v)
    rowAB[tid][1] = sc3 * s1s;               // B_r (scales b1)
  }
  __syncthreads();

  // pass 3: x = relu(A_r*v + B_r*b1) in-place; partials of sum(x^2)
#pragma unroll
  for (int rt = 0; rt < 4; ++rt) {
#pragma unroll
    for (int e = 0; e < 4; ++e) {
      int r = rt * 16 + quad * 4 + e;
      float Ar = rowAB[r][0];
      float Br = rowAB[r][1];
      float sx2 = 0.f;
#pragma unroll
      for (int jt = 0; jt < 4; ++jt) {
        float x = fmaxf(Ar * acc[rt][jt][e] + Br * bb1[jt], 0.f);
        acc[rt][jt][e] = x;
        sx2 += x * x;
      }
#pragma unroll
      for (int m = 1; m < 16; m <<= 1) sx2 += __shfl_xor(sx2, m);
      if (lane16 == 0) partX[r][wave] = sx2;
    }
  }
  __syncthreads();

  // pass 4: final expmap0 scalars + out[row][0]
  if (tid < 64) {
    float sx2 = partX[tid][0] + partX[tid][1] + partX[tid][2] + partX[tid][3];
    float n2 = fmaxf(sqrtf(sx2), MINV);
    float e2 = __expf(n2);
    float ie2 = 1.0f / e2;
    rowS[tid] = 0.5f * (e2 - ie2) / n2;      // sinh(n2)/n2
    out[(size_t)(rowBlock + tid) * 256] = 0.5f * (e2 + ie2);
  }
  __syncthreads();

  // pass 5: scaled store
#pragma unroll
  for (int rt = 0; rt < 4; ++rt) {
#pragma unroll
    for (int e = 0; e < 4; ++e) {
      int r = rt * 16 + quad * 4 + e;
      float scl = rowS[r];
      float* orow = out + (size_t)(rowBlock + r) * 256;
#pragma unroll
      for (int jt = 0; jt < 4; ++jt) {
        int c = colBase + jt * 16 + lane16;
        if (c < 255) orow[c + 1] = scl * acc[rt][jt][e];
      }
    }
  }
}

extern "C" void kernel_launch(void* const* d_in, const int* in_sizes, int n_in,
                              void* d_out, int out_size, void* d_ws, size_t ws_size,
                              hipStream_t stream) {
  const float* h     = (const float*)d_in[0];
  const float* W     = (const float*)d_in[1];
  const float* bias  = (const float*)d_in[2];
  const float* gamma = (const float*)d_in[3];
  const float* beta  = (const float*)d_in[4];
  float* out = (float*)d_out;

  __bf16* Wb  = (__bf16*)d_ws;                   // 128 KiB
  float* scal = (float*)((char*)d_ws + 131072);  // 3 floats

  prep_kernel<<<dim3(65), dim3(256), 0, stream>>>(W, bias, Wb, scal);
  hnn_kernel<<<dim3(4096), dim3(256), 0, stream>>>(h, Wb, bias, gamma, beta, scal, out);
}